// Round 6
// baseline (173.711 us; speedup 1.0000x reference)
//
#include <hip/hip_runtime.h>

#define TREES 32
#define PER   1023
#define NIPT  511
#define NINT  (TREES*NIPT)      // 16352
#define NLEAF (TREES*512)      // 16384
#define VLEAF 5000

typedef __bf16 bf16_t;
typedef bf16_t bf16x8 __attribute__((ext_vector_type(8)));
typedef float  f32x4  __attribute__((ext_vector_type(4)));

__device__ __forceinline__ float sigf(float x) { return 1.0f/(1.0f+__expf(-x)); }
__device__ __forceinline__ float tanh_fast(float x) { return 2.0f/(1.0f+__expf(-2.0f*x)) - 1.0f; }

__device__ __forceinline__ bf16x8 to_bf16x8(const float* p) {
  float4 a = *(const float4*)p;
  float4 b = *(const float4*)(p+4);
  bf16x8 r;
  r[0]=(bf16_t)a.x; r[1]=(bf16_t)a.y; r[2]=(bf16_t)a.z; r[3]=(bf16_t)a.w;
  r[4]=(bf16_t)b.x; r[5]=(bf16_t)b.y; r[6]=(bf16_t)b.z; r[7]=(bf16_t)b.w;
  return r;
}
__device__ __forceinline__ bf16x8 zero_bf16x8() {
  bf16x8 r;
  #pragma unroll
  for (int i=0;i<8;++i) r[i]=(bf16_t)0.0f;
  return r;
}

// ---- LDS B-staging: N-major [NCOLS][KB bytes] at ROWB stride (pad spreads banks)
template<int NCOLS, int KB, int ROWB, int NTHR>
__device__ __forceinline__ void stage_B(const bf16_t* __restrict__ src, char* lds, int tid) {
  const char* s = (const char*)src;
  for (int off = tid*16; off < NCOLS*KB; off += NTHR*16) {
    int col = off / KB;
    int ko  = off - col*KB;
    *(float4*)(lds + col*ROWB + ko) = *(const float4*)(s + off);
  }
}
__device__ __forceinline__ bf16x8 ldsB(const char* lds, int col, int kb, int rowb) {
  return *(const bf16x8*)(lds + col*rowb + kb);
}

// ---------------- weight packing (bf16, N-major) ----------------
__global__ __launch_bounds__(256) void convert_weights(
    const float* __restrict__ W_iou, const float* __restrict__ W_f,
    const float* __restrict__ U_iou, const float* __restrict__ U_f,
    const float* __restrict__ W_leaf,
    bf16_t* __restrict__ Wpt, bf16_t* __restrict__ Upt, bf16_t* __restrict__ WLt)
{
  const int n1 = 512*128;
  const int total = 2*n1 + 384*192;
  for (int idx = blockIdx.x*256 + threadIdx.x; idx < total; idx += gridDim.x*256) {
    if (idx < n1) {
      int cc = idx >> 7, k = idx & 127;
      Wpt[idx] = (bf16_t)(cc < 384 ? W_iou[k*384+cc] : W_f[k*128+cc-384]);
    } else if (idx < 2*n1) {
      int q = idx - n1;
      int cc = q >> 7, k = q & 127;
      Upt[q] = (bf16_t)(cc < 384 ? U_iou[k*384+cc] : U_f[k*128+cc-384]);
    } else {
      int q = idx - 2*n1;
      int cc = q / 192, k = q - cc*192;
      int cm = cc < 128 ? cc : cc + 128;        // [gi,gg,go] from [gi,gf,gg,go]
      WLt[q] = (bf16_t)W_leaf[(k>>6)*32768 + (k&63)*512 + cm];
    }
  }
}

// ---------------- fused prep (blocks 0-255) + leaf (blocks 256-511) -----------
__global__ __launch_bounds__(512) void prep_leaf(
    const int* __restrict__ features, const int* __restrict__ vocabs,
    const float* __restrict__ emb_res, const float* __restrict__ emb_leaf,
    const float* __restrict__ b_iou, const float* __restrict__ b_f,
    const float* __restrict__ b_leaf,
    const bf16_t* __restrict__ Wpt, const bf16_t* __restrict__ WLt,
    bf16_t* __restrict__ wxb, bf16_t* __restrict__ h, float* __restrict__ cst)
{
  __shared__ __align__(16) char Blds[384*392];   // 150528 B >= 512*264
  const int tid = threadIdx.x, wave = tid>>6, lane = tid&63;
  const int rg = wave>>2, cs = wave&3;
  const int lg = lane>>4, col0 = lane&15;

  if (blockIdx.x < 256) {
    // ======== prep: wxb[ci] = bf16([emb@W_iou+b_iou | emb@W_f+b_f])
    stage_B<512,256,264,512>(Wpt, Blds, tid);
    __syncthreads();
    #pragma unroll
    for (int mi=0; mi<2; ++mi) {
      const int mt = rg + mi*2;
      int rowA = blockIdx.x*64 + mt*16 + (lane&15);
      if (rowA >= NINT) rowA = NINT-1;
      unsigned tree = (unsigned)rowA / 511u;
      int local = rowA - tree*511u;
      int feat = features[tree*1023 + local];
      const float* ep = emb_res + (size_t)feat*128 + lg*8;

      bf16x8 a[4];
      #pragma unroll
      for (int ks=0; ks<4; ++ks) a[ks] = to_bf16x8(ep + ks*32);

      f32x4 acc[8];
      #pragma unroll
      for (int j=0;j<8;++j) acc[j] = (f32x4){0.f,0.f,0.f,0.f};
      #pragma unroll
      for (int ks=0; ks<4; ++ks) {
        #pragma unroll
        for (int j=0; j<8; ++j) {
          bf16x8 b = ldsB(Blds, cs*128 + j*16 + col0, ks*64 + lg*16, 264);
          acc[j] = __builtin_amdgcn_mfma_f32_16x16x32_bf16(a[ks], b, acc[j], 0,0,0);
        }
      }
      #pragma unroll
      for (int j=0; j<8; ++j) {
        int c = cs*128 + j*16 + col0;
        float bias = (c < 384) ? b_iou[c] : b_f[c-384];
        #pragma unroll
        for (int r=0; r<4; ++r) {
          int ci = blockIdx.x*64 + mt*16 + lg*4 + r;
          if (ci >= NINT) ci = NINT-1;
          wxb[(size_t)ci*512 + c] = (bf16_t)(acc[j][r] + bias);
        }
      }
    }
  } else {
    // ======== leaf: block-diag K=192 GEMM, N=384 [gi|gg|go]
    stage_B<384,384,392,512>(WLt, Blds, tid);
    __syncthreads();
    const int lb = blockIdx.x - 256;
    #pragma unroll
    for (int mi=0; mi<2; ++mi) {
      const int mt = rg + mi*2;
      const int base = lb*64 + mt*16;
      int rA = base + (lane&15);
      int treeA = rA>>9, loA = rA&511;
      int nodeA = treeA*1023 + 511 + loA;
      int kkA = vocabs[nodeA]-1;
      int featA = features[nodeA];
      const float* xp = emb_leaf + ((size_t)kkA*VLEAF + featA)*64;

      f32x4 acc[6];
      #pragma unroll
      for (int j=0;j<6;++j) acc[j] = (f32x4){0.f,0.f,0.f,0.f};
      #pragma unroll
      for (int ks=0; ks<6; ++ks) {
        int k0 = ks*32 + lg*8;
        bf16x8 a = ((k0>>6) == kkA) ? to_bf16x8(xp + (k0&63)) : zero_bf16x8();
        #pragma unroll
        for (int g=0; g<3; ++g) {
          #pragma unroll
          for (int s=0; s<2; ++s) {
            bf16x8 b = ldsB(Blds, g*128 + cs*32 + s*16 + col0, ks*64 + lg*16, 392);
            acc[g*2+s] = __builtin_amdgcn_mfma_f32_16x16x32_bf16(a, b, acc[g*2+s], 0,0,0);
          }
        }
      }
      #pragma unroll
      for (int r=0; r<4; ++r) {
        int L = base + lg*4 + r;
        int tree = L>>9, lo = L&511;
        int node = tree*1023 + 511 + lo;
        int kk = vocabs[node]-1;
        const float* bl = b_leaf + kk*512;
        #pragma unroll
        for (int s=0; s<2; ++s) {
          int cc = cs*32 + s*16 + col0;
          float gi = acc[s][r]   + bl[cc];
          float gg = acc[2+s][r] + bl[256+cc];
          float go = acc[4+s][r] + bl[384+cc];
          float ck = sigf(gi)*tanh_fast(gg);
          float hk = sigf(go)*tanh_fast(ck);
          cst[(size_t)node*128+cc] = ck;
          h[(size_t)node*128+cc] = (bf16_t)hk;
        }
      }
    }
  }
}

// ---------------- levels 1..4 inside order-4 subtrees: 2 subtrees per block ---
// intermediates (orders 1-3) live in LDS; only order-4 h/c goes to global
__global__ __launch_bounds__(512) void subtree_mfma(
    const bf16_t* __restrict__ Upt, const bf16_t* __restrict__ wxb,
    bf16_t* __restrict__ h, float* __restrict__ cst)
{
  __shared__ __align__(16) char Blds[512*264];     // 135168 B
  __shared__ __align__(16) bf16_t st_h[2][14][136];
  __shared__ float st_c[2][14][132];
  const int tid = threadIdx.x, wave = tid>>6, lane = tid&63;
  const int rg = wave>>2, cs = wave&3;
  const int lg = lane>>4, col0 = lane&15;
  const int s = blockIdx.x*2 + rg;                 // subtree id 0..1023
  const int tree = s>>5;
  const int x = 31 + (s&31);                       // order-4 root local index
  const int L0 = ((x+1)<<4) - 1;                   // first leaf local index
  const size_t hb = (size_t)tree*1023*128;

  stage_B<512,256,264,512>(Upt, Blds, tid);
  __syncthreads();

  #pragma unroll
  for (int n=1; n<=4; ++n) {
    const int P = 1 << (4-n);
    const int rows2 = 2*P;
    const int cbase = (n>=2) ? (16 - (16>>(n-2))) : 0;   // child slot base (order n-1)
    const int pbs = 16 - (16>>(n-1));                    // parent slot base (order n)

    // ---- A fragments (child rows)
    int r = lane&15; if (r >= rows2) r = 0;
    bf16x8 a[4];
    if (n == 1) {
      const bf16_t* hp = h + hb + (size_t)(L0 + r)*128 + lg*8;
      #pragma unroll
      for (int ks=0; ks<4; ++ks) a[ks] = *(const bf16x8*)(hp + ks*32);
    } else {
      const bf16_t* hp = &st_h[rg][cbase + r][lg*8];
      #pragma unroll
      for (int ks=0; ks<4; ++ks) a[ks] = *(const bf16x8*)(hp + ks*32);
    }

    // ---- epilogue operand prefetch
    float wxv[2][2][4], cch[2][2][2];
    int pj[2];
    #pragma unroll
    for (int pp=0; pp<2; ++pp) {
      pj[pp] = 2*lg + pp;
      if (pj[pp] < P) {
        int plocal = ((x+1)<<(4-n)) - 1 + pj[pp];
        size_t wb = ((size_t)tree*511 + plocal)*512;
        #pragma unroll
        for (int s2=0; s2<2; ++s2) {
          int hcol = cs*32 + s2*16 + col0;
          #pragma unroll
          for (int g=0; g<4; ++g) wxv[pp][s2][g] = (float)wxb[wb + g*128 + hcol];
          if (n == 1) {
            size_t chl = hb + (size_t)(L0 + 2*pj[pp])*128;
            cch[pp][s2][0] = cst[chl + hcol];
            cch[pp][s2][1] = cst[chl + 128 + hcol];
          } else {
            cch[pp][s2][0] = st_c[rg][cbase + 2*pj[pp]][hcol];
            cch[pp][s2][1] = st_c[rg][cbase + 2*pj[pp]+1][hcol];
          }
        }
      }
    }

    // ---- MFMA
    f32x4 acc[8];
    #pragma unroll
    for (int gs=0; gs<8; ++gs) acc[gs] = (f32x4){0.f,0.f,0.f,0.f};
    #pragma unroll
    for (int ks=0; ks<4; ++ks) {
      #pragma unroll
      for (int gs=0; gs<8; ++gs) {
        bf16x8 b = ldsB(Blds, (gs>>1)*128 + cs*32 + (gs&1)*16 + col0, ks*64 + lg*16, 264);
        acc[gs] = __builtin_amdgcn_mfma_f32_16x16x32_bf16(a[ks], b, acc[gs], 0,0,0);
      }
    }

    // ---- LSTM combine + store (LDS for n<4, global for n==4)
    #pragma unroll
    for (int pp=0; pp<2; ++pp) {
      if (pj[pp] < P) {
        #pragma unroll
        for (int s2=0; s2<2; ++s2) {
          int hcol = cs*32 + s2*16 + col0;
          float iv = acc[s2][2*pp]   + acc[s2][2*pp+1]   + wxv[pp][s2][0];
          float ov = acc[2+s2][2*pp] + acc[2+s2][2*pp+1] + wxv[pp][s2][1];
          float uv = acc[4+s2][2*pp] + acc[4+s2][2*pp+1] + wxv[pp][s2][2];
          float wf = wxv[pp][s2][3];
          float fl = sigf(acc[6+s2][2*pp]   + wf);
          float fr = sigf(acc[6+s2][2*pp+1] + wf);
          float cf = fl*cch[pp][s2][0] + fr*cch[pp][s2][1];
          float cn = sigf(iv)*tanh_fast(uv) + cf;
          float hn = sigf(ov)*tanh_fast(cn);
          if (n < 4) {
            st_c[rg][pbs + pj[pp]][hcol] = cn;
            st_h[rg][pbs + pj[pp]][hcol] = (bf16_t)hn;
          } else {
            cst[hb + (size_t)x*128 + hcol] = cn;
            h[hb + (size_t)x*128 + hcol] = (bf16_t)hn;
          }
        }
      }
    }
    __syncthreads();
  }
}

// ---------------- tail levels n=5..9 + root head: one block per tree ----------
__global__ __launch_bounds__(512) void tree_tail(
    const bf16_t* __restrict__ Upt, const bf16_t* __restrict__ wxb,
    bf16_t* __restrict__ h, float* __restrict__ cst,
    const float* __restrict__ Wm, const float* __restrict__ bm,
    const float* __restrict__ Wv, const float* __restrict__ bv,
    const float* __restrict__ eps, float* __restrict__ out)
{
  __shared__ __align__(16) char Blds[512*264];
  __shared__ float hs[128];
  const int tid = threadIdx.x, wave = tid>>6, lane = tid&63;
  const int rg = wave>>2, cs = wave&3;
  const int lg = lane>>4, col0 = lane&15;
  const int tree = blockIdx.x;
  const size_t hb = (size_t)tree*1023*128;

  stage_B<512,256,264,512>(Upt, Blds, tid);
  __syncthreads();

  for (int n = 5; n <= 9; ++n) {
    const int P = 1 << (9-n);
    const int rows2 = 2*P;
    const int mtiles = (rows2 >= 16) ? (rows2 >> 4) : 1;
    const int cbase = 2*P - 1;

    for (int mt = rg; mt < mtiles; mt += 2) {
      const int rb = mt*16;
      int cr = rb + (lane&15);
      if (cr >= rows2) cr = 0;
      const bf16_t* hp = h + hb + (size_t)(cbase + cr)*128 + lg*8;
      bf16x8 a[4];
      #pragma unroll
      for (int ks=0; ks<4; ++ks) a[ks] = *(const bf16x8*)(hp + ks*32);

      float wxv[2][2][4], cch[2][2][2];
      int pj[2], plocal[2];
      #pragma unroll
      for (int pp=0; pp<2; ++pp) {
        pj[pp] = (rb>>1) + lg*2 + pp;
        plocal[pp] = P - 1 + pj[pp];
        if (pj[pp] < P) {
          size_t wb = ((size_t)tree*511 + plocal[pp])*512;
          size_t chl = hb + (size_t)(cbase + 2*pj[pp])*128;
          #pragma unroll
          for (int s2=0; s2<2; ++s2) {
            int hcol = cs*32 + s2*16 + col0;
            #pragma unroll
            for (int g=0; g<4; ++g) wxv[pp][s2][g] = (float)wxb[wb + g*128 + hcol];
            cch[pp][s2][0] = cst[chl + hcol];
            cch[pp][s2][1] = cst[chl + 128 + hcol];
          }
        }
      }

      f32x4 acc[8];
      #pragma unroll
      for (int gs=0; gs<8; ++gs) acc[gs] = (f32x4){0.f,0.f,0.f,0.f};
      #pragma unroll
      for (int ks=0; ks<4; ++ks) {
        #pragma unroll
        for (int gs=0; gs<8; ++gs) {
          bf16x8 b = ldsB(Blds, (gs>>1)*128 + cs*32 + (gs&1)*16 + col0, ks*64 + lg*16, 264);
          acc[gs] = __builtin_amdgcn_mfma_f32_16x16x32_bf16(a[ks], b, acc[gs], 0,0,0);
        }
      }

      #pragma unroll
      for (int pp=0; pp<2; ++pp) {
        if (pj[pp] < P) {
          size_t pno = hb + (size_t)plocal[pp]*128;
          #pragma unroll
          for (int s2=0; s2<2; ++s2) {
            int hcol = cs*32 + s2*16 + col0;
            float iv = acc[s2][2*pp]   + acc[s2][2*pp+1]   + wxv[pp][s2][0];
            float ov = acc[2+s2][2*pp] + acc[2+s2][2*pp+1] + wxv[pp][s2][1];
            float uv = acc[4+s2][2*pp] + acc[4+s2][2*pp+1] + wxv[pp][s2][2];
            float wf = wxv[pp][s2][3];
            float fl = sigf(acc[6+s2][2*pp]   + wf);
            float fr = sigf(acc[6+s2][2*pp+1] + wf);
            float cf = fl*cch[pp][s2][0] + fr*cch[pp][s2][1];
            float cn = sigf(iv)*tanh_fast(uv) + cf;
            float hn = sigf(ov)*tanh_fast(cn);
            cst[pno + hcol] = cn;
            h[pno + hcol] = (bf16_t)hn;
            if (n == 9) hs[hcol] = hn;     // only pj==0 reaches here at n=9
          }
        }
      }
    }
    __threadfence_block();
    __syncthreads();
  }

  // fused root head
  if (tid < 64) {
    const int j = tid;
    float am = 0.f, av = 0.f;
    #pragma unroll 4
    for (int i=0;i<128;++i) {
      float hv = hs[i];
      am += hv*Wm[i*64+j];
      av += hv*Wv[i*64+j];
    }
    float zm = am + bm[j];
    float zv = av + bv[j];
    int idx = tree*64 + j;
    out[idx]        = zm + eps[idx]*__expf(0.5f*zv);
    out[2048 + idx] = zm;
    out[4096 + idx] = zv;
  }
}

extern "C" void kernel_launch(void* const* d_in, const int* in_sizes, int n_in,
                              void* d_out, int out_size, void* d_ws, size_t ws_size,
                              hipStream_t stream) {
  const int*   features = (const int*)  d_in[0];
  const int*   vocabs   = (const int*)  d_in[1];
  // d_in[2..5]: static topology (derived in-kernel)
  const float* eps      = (const float*)d_in[6];
  const float* emb_res  = (const float*)d_in[7];
  const float* emb_leaf = (const float*)d_in[8];
  const float* W_leaf   = (const float*)d_in[9];
  const float* b_leaf   = (const float*)d_in[10];
  const float* W_iou    = (const float*)d_in[11];
  const float* b_iou    = (const float*)d_in[12];
  const float* U_iou    = (const float*)d_in[13];
  const float* W_f      = (const float*)d_in[14];
  const float* b_f      = (const float*)d_in[15];
  const float* U_f      = (const float*)d_in[16];
  const float* Wm       = (const float*)d_in[17];
  const float* bm       = (const float*)d_in[18];
  const float* Wv       = (const float*)d_in[19];
  const float* bv       = (const float*)d_in[20];

  char* wsb = (char*)d_ws;
  bf16_t* h   = (bf16_t*)wsb;                                   // NNODES*128 bf16
  float*  cst = (float*)(wsb + 8388608);                        // NNODES*128 f32
  bf16_t* wxb = (bf16_t*)(wsb + 8388608 + 16777216);            // NINT*512 bf16
  bf16_t* Wpt = (bf16_t*)(wsb + 8388608 + 16777216 + 33554432);
  bf16_t* Upt = Wpt + 512*128;
  bf16_t* WLt = Upt + 512*128;
  float* out = (float*)d_out;

  convert_weights<<<200, 256, 0, stream>>>(W_iou, W_f, U_iou, U_f, W_leaf, Wpt, Upt, WLt);
  prep_leaf<<<512, 512, 0, stream>>>(features, vocabs, emb_res, emb_leaf,
                                     b_iou, b_f, b_leaf, Wpt, WLt, wxb, h, cst);
  subtree_mfma<<<512, 512, 0, stream>>>(Upt, wxb, h, cst);
  tree_tail<<<TREES, 512, 0, stream>>>(Upt, wxb, h, cst, Wm, bm, Wv, bv, eps, out);
}